// Round 15
// baseline (17.114 us; speedup 1.0000x reference)
//
#include <hip/hip_runtime.h>
#include <stdint.h>

// 7x7 median blur, zero padding, on (image+1)/2, then *2-1, clip [-1,1].
// clamp01 commutes with median+clip; 6-bit RTN quantization q=floor(31.5v+32)
// = round(63*clamp01((v+1)/2)); absmax = 1/63 + 2^-8 (bf16 compare) =
// 0.01953125 < 2e-2, deterministic (proven R7/R12/R13 -- identical math).
// R15 = R14 (registers-only halo: each lane owns 4 columns, 64 lanes = full
// 256-col width, one wave = one row-run, zero LDS, zero barriers, float4 IO,
// dual-window shared transpose, dual radix select) + BPERMUTE DIVERGENCE FIX:
// R14 wrote `edge ? 0 : BPERM(...)`; ds_bpermute is convergent, so clang
// keeps it inside a divergent branch -- with lane 0/63 masked out of exec,
// pulls FROM those lanes return 0 (inactive source) and lane 1/62 windows
// corrupt. Fix: all 12 bpermutes execute UNCONDITIONALLY (uniform exec;
// wrapped indices pull real values), edge zeroing applied to the RESULTS
// via plain cndmask selects.

#define IMG_H 256
#define IMG_W 256
#define RROWS 4
#define RUNS  (IMG_H / RROWS)    // 64
#define W4    (IMG_W / 4)        // 64 float4 per row

#define PERM(a,b,s) __builtin_amdgcn_perm((a),(b),(s))
#define BPERM(i,v)  ((uint32_t)__builtin_amdgcn_ds_bpermute((int)(i),(int)(v)))

struct Planes6 { uint32_t pL[6], pH[6]; };  // pL = cols j..j+3, pH = j+4..j+6

// Ld bytes 0-3 = planes 0-3 (8-row masks of column d); Hd bytes 0-1 =
// planes 4-5 (bytes 2-3 zero). Output: plane i as byte-packed column masks.
__device__ __forceinline__ Planes6 transpose6(
    uint32_t L0, uint32_t L1, uint32_t L2, uint32_t L3,
    uint32_t L4, uint32_t L5, uint32_t L6,
    uint32_t H0, uint32_t H1, uint32_t H2, uint32_t H3,
    uint32_t H4, uint32_t H5, uint32_t H6)
{
    Planes6 P;
    {   // planes 0..3 from L words
        uint32_t za1 = PERM(L1, L0, 0x05010400u), zb1 = PERM(L1, L0, 0x07030602u);
        uint32_t za2 = PERM(L3, L2, 0x05010400u), zb2 = PERM(L3, L2, 0x07030602u);
        uint32_t za3 = PERM(L5, L4, 0x05010400u), zb3 = PERM(L5, L4, 0x07030602u);
        uint32_t za4 = PERM(0u, L6, 0x05010400u), zb4 = PERM(0u, L6, 0x07030602u);
        P.pL[0] = PERM(za2, za1, 0x05040100u);  P.pH[0] = PERM(za4, za3, 0x05040100u);
        P.pL[1] = PERM(za2, za1, 0x07060302u);  P.pH[1] = PERM(za4, za3, 0x07060302u);
        P.pL[2] = PERM(zb2, zb1, 0x05040100u);  P.pH[2] = PERM(zb4, zb3, 0x05040100u);
        P.pL[3] = PERM(zb2, zb1, 0x07060302u);  P.pH[3] = PERM(zb4, zb3, 0x07060302u);
    }
    {   // planes 4..5 from H words (bytes 0-1 only)
        uint32_t za1 = PERM(H1, H0, 0x05010400u);
        uint32_t za2 = PERM(H3, H2, 0x05010400u);
        uint32_t za3 = PERM(H5, H4, 0x05010400u);
        uint32_t za4 = PERM(0u, H6, 0x05010400u);
        P.pL[4] = PERM(za2, za1, 0x05040100u);  P.pH[4] = PERM(za4, za3, 0x05040100u);
        P.pL[5] = PERM(za2, za1, 0x07060302u);  P.pH[5] = PERM(za4, za3, 0x07060302u);
    }
    return P;
}

__device__ __forceinline__ uint32_t quant6(float v) {
    float t = fmaf(v, 31.5f, 32.0f);       // round(63*clamp01((v+1)/2))
    t = fminf(fmaxf(t, 0.0f), 63.0f);      // v_med3_f32
    return (uint32_t)t;                    // 0..63
}

// Fused dual-row roll: q0 (older) enters at bit6, q1 (newest) at bit7 after
// one >>2 shift. Spread mults are carry-free; masks kill cross terms.
__device__ __forceinline__ void roll2(uint32_t& lo, uint32_t& hi,
                                      uint32_t q0, uint32_t q1) {
    uint32_t n0 = ((q0 & 15u) * 0x08102040u) & 0x40404040u;
    uint32_t n1 = ((q1 & 15u) * 0x10204080u) & 0x80808080u;
    lo = ((lo >> 2) & 0x3F3F3F3Fu) | n0 | n1;
    uint32_t m0 = ((q0 >> 4) * 0x08102040u) & 0x00004040u;
    uint32_t m1 = ((q1 >> 4) * 0x10204080u) & 0x00008080u;
    hi = ((hi >> 2) & 0x00003F3Fu) | m0 | m1;
}

// Dual radix select (rank 25-from-top of 49). Window A = row-bits 0-6,
// window B = bits 1-7, chosen by act-mask init. Final round trimmed.
__device__ __forceinline__ void select2(const Planes6& P,
                                        uint32_t& medA, uint32_t& medB)
{
    uint32_t acloA = 0x7F7F7F7Fu, achiA = 0x007F7F7Fu, kA = 25u; medA = 0u;
    uint32_t acloB = 0xFEFEFEFEu, achiB = 0x00FEFEFEu, kB = 25u; medB = 0u;
#pragma unroll
    for (int p = 5; p >= 1; --p) {
        {
            uint32_t ol = acloA & P.pL[p], oh = achiA & P.pH[p];
            uint32_t c1 = (uint32_t)(__popc(ol) + __popc(oh));
            bool b = (kA <= c1);
            acloA = b ? ol : (acloA ^ ol);
            achiA = b ? oh : (achiA ^ oh);
            kA    = b ? kA : (kA - c1);
            medA  = medA + medA + (b ? 1u : 0u);
        }
        {
            uint32_t ol = acloB & P.pL[p], oh = achiB & P.pH[p];
            uint32_t c1 = (uint32_t)(__popc(ol) + __popc(oh));
            bool b = (kB <= c1);
            acloB = b ? ol : (acloB ^ ol);
            achiB = b ? oh : (achiB ^ oh);
            kB    = b ? kB : (kB - c1);
            medB  = medB + medB + (b ? 1u : 0u);
        }
    }
    {   // p = 0, trimmed: only the last median bit is live
        uint32_t c1A = (uint32_t)(__popc(acloA & P.pL[0]) + __popc(achiA & P.pH[0]));
        medA = medA + medA + ((kA <= c1A) ? 1u : 0u);
        uint32_t c1B = (uint32_t)(__popc(acloB & P.pL[0]) + __popc(achiB & P.pH[0]));
        medB = medB + medB + ((kB <= c1B) ? 1u : 0u);
    }
}

__global__ __launch_bounds__(256, 3)
void median7_kernel(const float* __restrict__ img, float* __restrict__ out) {
    const int lane = threadIdx.x & 63;
    const int wid  = blockIdx.x * 4 + (threadIdx.x >> 6);  // wave = one row-run
    const int pl   = wid / RUNS;
    const int run  = wid % RUNS;
    const int y0   = run * RROWS;

    const float4* ip4 = (const float4*)(img + (size_t)pl * (IMG_H * IMG_W));
    float*        op  = out + (size_t)pl * (IMG_H * IMG_W);

    // Own-column state: columns 4*lane .. 4*lane+3.
    uint32_t vlo[4] = {0u, 0u, 0u, 0u};
    uint32_t vhi[4] = {0u, 0u, 0u, 0u};

    auto loadrow = [&](int r) -> float4 {
        return ip4[min(max(r, 0), IMG_H - 1) * W4 + lane];
    };
    auto ingest = [&](float4 a, float4 b, int r0, int r1) {
        const bool ok0 = (uint32_t)r0 < (uint32_t)IMG_H;
        const bool ok1 = (uint32_t)r1 < (uint32_t)IMG_H;
        uint32_t q00 = ok0 ? quant6(a.x) : 0u, q10 = ok1 ? quant6(b.x) : 0u;
        uint32_t q01 = ok0 ? quant6(a.y) : 0u, q11 = ok1 ? quant6(b.y) : 0u;
        uint32_t q02 = ok0 ? quant6(a.z) : 0u, q12 = ok1 ? quant6(b.z) : 0u;
        uint32_t q03 = ok0 ? quant6(a.w) : 0u, q13 = ok1 ? quant6(b.w) : 0u;
        roll2(vlo[0], vhi[0], q00, q10);
        roll2(vlo[1], vhi[1], q01, q11);
        roll2(vlo[2], vhi[2], q02, q12);
        roll2(vlo[3], vhi[3], q03, q13);
    };

    const int  idxL  = ((lane + 63) & 63) << 2;   // pull from lane-1 (wraps)
    const int  idxR  = ((lane +  1) & 63) << 2;   // pull from lane+1 (wraps)
    const bool edgeL = (lane == 0), edgeR = (lane == 63);

    auto epoch = [&](int yA) {
        // Halo: cols -3..-1 = lane-1's cols 1,2,3 ; cols +4..+6 = lane+1's
        // cols 0,1,2. ALL bpermutes run unconditionally (uniform exec --
        // convergent op must not sit in a divergent branch, R14's bug);
        // edge-lane results are then zeroed (= image zero-pad) via cndmask.
        uint32_t bl1 = BPERM(idxL, vlo[1]), bh1 = BPERM(idxL, vhi[1]);
        uint32_t bl2 = BPERM(idxL, vlo[2]), bh2 = BPERM(idxL, vhi[2]);
        uint32_t bl3 = BPERM(idxL, vlo[3]), bh3 = BPERM(idxL, vhi[3]);
        uint32_t br0 = BPERM(idxR, vlo[0]), bg0 = BPERM(idxR, vhi[0]);
        uint32_t br1 = BPERM(idxR, vlo[1]), bg1 = BPERM(idxR, vhi[1]);
        uint32_t br2 = BPERM(idxR, vlo[2]), bg2 = BPERM(idxR, vhi[2]);

        uint32_t Lc[10], Hc[10];
        Lc[0] = edgeL ? 0u : bl1;  Hc[0] = edgeL ? 0u : bh1;
        Lc[1] = edgeL ? 0u : bl2;  Hc[1] = edgeL ? 0u : bh2;
        Lc[2] = edgeL ? 0u : bl3;  Hc[2] = edgeL ? 0u : bh3;
        Lc[3] = vlo[0]; Lc[4] = vlo[1]; Lc[5] = vlo[2]; Lc[6] = vlo[3];
        Hc[3] = vhi[0]; Hc[4] = vhi[1]; Hc[5] = vhi[2]; Hc[6] = vhi[3];
        Lc[7] = edgeR ? 0u : br0;  Hc[7] = edgeR ? 0u : bg0;
        Lc[8] = edgeR ? 0u : br1;  Hc[8] = edgeR ? 0u : bg1;
        Lc[9] = edgeR ? 0u : br2;  Hc[9] = edgeR ? 0u : bg2;

        float4 oA, oB;
        {   // output column 4*lane+0: window cols Lc[0..6]
            Planes6 P = transpose6(Lc[0],Lc[1],Lc[2],Lc[3],Lc[4],Lc[5],Lc[6],
                                   Hc[0],Hc[1],Hc[2],Hc[3],Hc[4],Hc[5],Hc[6]);
            uint32_t mA, mB; select2(P, mA, mB);
            oA.x = fmaf((float)mA, 2.0f / 63.0f, -1.0f);
            oB.x = fmaf((float)mB, 2.0f / 63.0f, -1.0f);
        }
        {   // output column +1
            Planes6 P = transpose6(Lc[1],Lc[2],Lc[3],Lc[4],Lc[5],Lc[6],Lc[7],
                                   Hc[1],Hc[2],Hc[3],Hc[4],Hc[5],Hc[6],Hc[7]);
            uint32_t mA, mB; select2(P, mA, mB);
            oA.y = fmaf((float)mA, 2.0f / 63.0f, -1.0f);
            oB.y = fmaf((float)mB, 2.0f / 63.0f, -1.0f);
        }
        {   // output column +2
            Planes6 P = transpose6(Lc[2],Lc[3],Lc[4],Lc[5],Lc[6],Lc[7],Lc[8],
                                   Hc[2],Hc[3],Hc[4],Hc[5],Hc[6],Hc[7],Hc[8]);
            uint32_t mA, mB; select2(P, mA, mB);
            oA.z = fmaf((float)mA, 2.0f / 63.0f, -1.0f);
            oB.z = fmaf((float)mB, 2.0f / 63.0f, -1.0f);
        }
        {   // output column +3
            Planes6 P = transpose6(Lc[3],Lc[4],Lc[5],Lc[6],Lc[7],Lc[8],Lc[9],
                                   Hc[3],Hc[4],Hc[5],Hc[6],Hc[7],Hc[8],Hc[9]);
            uint32_t mA, mB; select2(P, mA, mB);
            oA.w = fmaf((float)mA, 2.0f / 63.0f, -1.0f);
            oB.w = fmaf((float)mB, 2.0f / 63.0f, -1.0f);
        }
        ((float4*)(op + (size_t)yA * IMG_W))[lane] = oA;
        ((float4*)(op + (size_t)(yA + 1) * IMG_W))[lane] = oB;
    };

    // Prologue: rows y0-3 .. y0+4 (8 rows; top masked, bottom clamped+masked
    // -- at run 63, y0+4 = 256 is off-image: R10's lesson).
    {
        float4 a0 = loadrow(y0 - 3), b0 = loadrow(y0 - 2);
        float4 a1 = loadrow(y0 - 1), b1 = loadrow(y0 + 0);
        float4 a2 = loadrow(y0 + 1), b2 = loadrow(y0 + 2);
        float4 a3 = loadrow(y0 + 3), b3 = loadrow(y0 + 4);
        ingest(a0, b0, y0 - 3, y0 - 2);
        ingest(a1, b1, y0 - 1, y0 + 0);
        ingest(a2, b2, y0 + 1, y0 + 2);
        ingest(a3, b3, y0 + 3, y0 + 4);
    }
    // Prefetch epoch-1 rows (consumed after epoch 0's selects).
    float4 p5 = loadrow(y0 + 5), p6 = loadrow(y0 + 6);

    epoch(y0);                         // outputs rows y0, y0+1
    ingest(p5, p6, y0 + 5, y0 + 6);    // rows y0+5, y0+6 (masked past bottom)
    epoch(y0 + 2);                     // outputs rows y0+2, y0+3
}

extern "C" void kernel_launch(void* const* d_in, const int* in_sizes, int n_in,
                              void* d_out, int out_size, void* d_ws, size_t ws_size,
                              hipStream_t stream) {
    const float* img = (const float*)d_in[0];   // image; cover_image unused
    float* out = (float*)d_out;
    const int planes = in_sizes[0] / (IMG_H * IMG_W);   // 16*3 = 48
    dim3 grid(planes * RUNS / 4);               // 768 blocks (4 waves each)
    dim3 block(256);
    median7_kernel<<<grid, block, 0, stream>>>(img, out);
}

// Round 16
// 15.185 us; speedup vs baseline: 1.1271x; 1.1271x over previous
//
#include <hip/hip_runtime.h>
#include <stdint.h>

// 7x7 median blur, zero padding, on (image+1)/2, then *2-1, clip [-1,1].
// clamp01 commutes with median+clip; 6-bit RTN quantization q=floor(31.5v+32)
// = round(63*clamp01((v+1)/2)); absmax = 1/63 + 2^-8 (bf16 compare) =
// 0.01953125 < 2e-2, deterministic (proven R7/R12/R13 -- identical math).
// R16 = R13 + 4-ROW SUPER-EPOCHS: rows y0+3..y0+6 are always in-image at
// RROWS=8, so both V-states of a 4-row batch ({after row+4, after row+6})
// are built together and stored as ONE ulonglong2 -> 1 ds_write_b128 +
// 6 ds_read_b128 + 1 barrier per 4 rows (R13: 2 writes + 12 reads + 2
// barriers) and no bottom clamps for rows +3..+7. Per 2-row pair: one
// byte-transpose (24 v_perm) serves BOTH outputs (window A = row-bits 0-6,
// B = bits 1-7, chosen by act-mask init 0x7F.../0xFE...); dual interleaved
// popcount radix select rank 25-from-top of 49, final round trimmed.
// Prefetch of the next batch's 4 rows is issued at super-epoch start and
// consumed after the selects (R7 load-early/consume-late order).

#define IMG_H 256
#define IMG_W 256
#define RROWS 8
#define RUNS  (IMG_H / RROWS)    // 32
typedef unsigned long long u64;

#define PERM(a,b,s) __builtin_amdgcn_perm((a),(b),(s))

struct Planes6 { uint32_t pL[6], pH[6]; };  // pL = cols 0-3, pH = cols 4-6

// Ld bytes 0-3 = planes 0-3 (8-row masks of column d); Hd bytes 0-1 =
// planes 4-5. Output: plane i as byte-packed column masks.
__device__ __forceinline__ Planes6 transpose6(
    uint32_t L0, uint32_t L1, uint32_t L2, uint32_t L3,
    uint32_t L4, uint32_t L5, uint32_t L6,
    uint32_t H0, uint32_t H1, uint32_t H2, uint32_t H3,
    uint32_t H4, uint32_t H5, uint32_t H6)
{
    Planes6 P;
    {   // planes 0..3 from L words
        uint32_t za1 = PERM(L1, L0, 0x05010400u), zb1 = PERM(L1, L0, 0x07030602u);
        uint32_t za2 = PERM(L3, L2, 0x05010400u), zb2 = PERM(L3, L2, 0x07030602u);
        uint32_t za3 = PERM(L5, L4, 0x05010400u), zb3 = PERM(L5, L4, 0x07030602u);
        uint32_t za4 = PERM(0u, L6, 0x05010400u), zb4 = PERM(0u, L6, 0x07030602u);
        P.pL[0] = PERM(za2, za1, 0x05040100u);  P.pH[0] = PERM(za4, za3, 0x05040100u);
        P.pL[1] = PERM(za2, za1, 0x07060302u);  P.pH[1] = PERM(za4, za3, 0x07060302u);
        P.pL[2] = PERM(zb2, zb1, 0x05040100u);  P.pH[2] = PERM(zb4, zb3, 0x05040100u);
        P.pL[3] = PERM(zb2, zb1, 0x07060302u);  P.pH[3] = PERM(zb4, zb3, 0x07060302u);
    }
    {   // planes 4..5 from H words (bytes 0-1 only)
        uint32_t za1 = PERM(H1, H0, 0x05010400u);
        uint32_t za2 = PERM(H3, H2, 0x05010400u);
        uint32_t za3 = PERM(H5, H4, 0x05010400u);
        uint32_t za4 = PERM(0u, H6, 0x05010400u);
        P.pL[4] = PERM(za2, za1, 0x05040100u);  P.pH[4] = PERM(za4, za3, 0x05040100u);
        P.pL[5] = PERM(za2, za1, 0x07060302u);  P.pH[5] = PERM(za4, za3, 0x07060302u);
    }
    return P;
}

__device__ __forceinline__ uint32_t quant6(float v) {
    float t = fmaf(v, 31.5f, 32.0f);       // round(63*clamp01((v+1)/2))
    t = fminf(fmaxf(t, 0.0f), 63.0f);      // v_med3_f32
    return (uint32_t)t;                    // 0..63
}

// Fused dual-row roll: q0 (older) enters at bit6, q1 (newest) at bit7 after
// one >>2 shift. Spread mults are carry-free; masks kill cross terms.
__device__ __forceinline__ void roll2(uint32_t& lo, uint32_t& hi,
                                      uint32_t q0, uint32_t q1) {
    uint32_t n0 = ((q0 & 15u) * 0x08102040u) & 0x40404040u;
    uint32_t n1 = ((q1 & 15u) * 0x10204080u) & 0x80808080u;
    lo = ((lo >> 2) & 0x3F3F3F3Fu) | n0 | n1;
    uint32_t m0 = ((q0 >> 4) * 0x08102040u) & 0x00004040u;
    uint32_t m1 = ((q1 >> 4) * 0x10204080u) & 0x00008080u;
    hi = ((hi >> 2) & 0x00003F3Fu) | m0 | m1;
}

// Dual radix select over shared planes. Window A = row-bits 0-6 (output yA),
// window B = bits 1-7 (output yA+1), chosen by act-mask init alone.
// Final round trimmed: only the median's last bit is live.
__device__ __forceinline__ void select2_store(
    const Planes6& P, float* __restrict__ op, int yA, int x)
{
    uint32_t acloA = 0x7F7F7F7Fu, achiA = 0x007F7F7Fu, kA = 25u, medA = 0u;
    uint32_t acloB = 0xFEFEFEFEu, achiB = 0x00FEFEFEu, kB = 25u, medB = 0u;
#pragma unroll
    for (int p = 5; p >= 1; --p) {
        {
            uint32_t ol = acloA & P.pL[p], oh = achiA & P.pH[p];
            uint32_t c1 = (uint32_t)(__popc(ol) + __popc(oh));
            bool b = (kA <= c1);
            acloA = b ? ol : (acloA ^ ol);
            achiA = b ? oh : (achiA ^ oh);
            kA    = b ? kA : (kA - c1);
            medA  = medA + medA + (b ? 1u : 0u);
        }
        {
            uint32_t ol = acloB & P.pL[p], oh = achiB & P.pH[p];
            uint32_t c1 = (uint32_t)(__popc(ol) + __popc(oh));
            bool b = (kB <= c1);
            acloB = b ? ol : (acloB ^ ol);
            achiB = b ? oh : (achiB ^ oh);
            kB    = b ? kB : (kB - c1);
            medB  = medB + medB + (b ? 1u : 0u);
        }
    }
    {   // p = 0, trimmed
        uint32_t c1A = (uint32_t)(__popc(acloA & P.pL[0]) + __popc(achiA & P.pH[0]));
        medA = medA + medA + ((kA <= c1A) ? 1u : 0u);
        uint32_t c1B = (uint32_t)(__popc(acloB & P.pL[0]) + __popc(achiB & P.pH[0]));
        medB = medB + medB + ((kB <= c1B) ? 1u : 0u);
    }
    __builtin_nontemporal_store(fmaf((float)medA, 2.0f / 63.0f, -1.0f),
                                &op[yA * IMG_W + x]);
    __builtin_nontemporal_store(fmaf((float)medB, 2.0f / 63.0f, -1.0f),
                                &op[(yA + 1) * IMG_W + x]);
}

__global__ __launch_bounds__(256, 6)
void median7_kernel(const float* __restrict__ img, float* __restrict__ out) {
    const int x   = threadIdx.x;              // column 0..255
    const int pl  = blockIdx.x / RUNS;        // b*c plane
    const int run = blockIdx.x % RUNS;
    const int y0  = run * RROWS;

    const float* ip = img + (size_t)pl * (IMG_H * IMG_W);
    float*       op = out + (size_t)pl * (IMG_H * IMG_W);

    // Slot = {V after batch-row 2, V after batch-row 4} for one column.
    // 3 zero guard slots/side = column zero-padding. 16B stride, 16B aligned.
    __shared__ ulonglong2 VL[2][IMG_W + 6];
    if (x < 3) {
        const ulonglong2 z = make_ulonglong2(0ULL, 0ULL);
        VL[0][x] = z; VL[1][x] = z;
        VL[0][IMG_W + 3 + x] = z; VL[1][IMG_W + 3 + x] = z;
    }

    uint32_t vlo = 0u, vhi = 0u;

    // Prologue: rows y0-3 .. y0+2 (top-masked; bottom always valid).
    {
        float pv[6];
#pragma unroll
        for (int j = 0; j < 6; ++j) pv[j] = ip[max(y0 - 3 + j, 0) * IMG_W + x];
        uint32_t q[6];
#pragma unroll
        for (int j = 0; j < 6; ++j)
            q[j] = (y0 - 3 + j) >= 0 ? quant6(pv[j]) : 0u;
        roll2(vlo, vhi, q[0], q[1]);
        roll2(vlo, vhi, q[2], q[3]);
        roll2(vlo, vhi, q[4], q[5]);
    }
    // Batch 0: rows y0+3..y0+6 -- ALWAYS in-image (y0 <= 248 -> <= 254).
    uint32_t sAlo, sAhi;
    {
        float f0 = ip[(y0 + 3) * IMG_W + x], f1 = ip[(y0 + 4) * IMG_W + x];
        float f2 = ip[(y0 + 5) * IMG_W + x], f3 = ip[(y0 + 6) * IMG_W + x];
        roll2(vlo, vhi, quant6(f0), quant6(f1));
        sAlo = vlo; sAhi = vhi;                       // V after y0+4
        roll2(vlo, vhi, quant6(f2), quant6(f3));      // V after y0+6
    }
    VL[0][3 + x] = make_ulonglong2(((u64)sAhi << 32) | sAlo,
                                   ((u64)vhi  << 32) | vlo);
    __syncthreads();

    // ---- Super-epoch 0: outputs y0..y0+3 ----
    {
        const ulonglong2* qp = &VL[0][x];
        ulonglong2 n0 = qp[0], n1 = qp[1], n2 = qp[2];
        ulonglong2 n4 = qp[4], n5 = qp[5], n6 = qp[6];

        // Prefetch batch 1 rows y0+7..y0+10 (y0+7 always valid; rest clamped).
        float g0 = ip[(y0 + 7) * IMG_W + x];
        float g1 = ip[min(y0 + 8,  IMG_H - 1) * IMG_W + x];
        float g2 = ip[min(y0 + 9,  IMG_H - 1) * IMG_W + x];
        float g3 = ip[min(y0 + 10, IMG_H - 1) * IMG_W + x];

        // Pair 0 (outputs y0, y0+1): V after y0+4 = snapshot A.
        Planes6 P0 = transpose6(
            (uint32_t)n0.x, (uint32_t)n1.x, (uint32_t)n2.x, sAlo,
            (uint32_t)n4.x, (uint32_t)n5.x, (uint32_t)n6.x,
            (uint32_t)(n0.x >> 32), (uint32_t)(n1.x >> 32), (uint32_t)(n2.x >> 32), sAhi,
            (uint32_t)(n4.x >> 32), (uint32_t)(n5.x >> 32), (uint32_t)(n6.x >> 32));
        select2_store(P0, op, y0, x);

        // Pair 1 (outputs y0+2, y0+3): V after y0+6 = current.
        Planes6 P1 = transpose6(
            (uint32_t)n0.y, (uint32_t)n1.y, (uint32_t)n2.y, vlo,
            (uint32_t)n4.y, (uint32_t)n5.y, (uint32_t)n6.y,
            (uint32_t)(n0.y >> 32), (uint32_t)(n1.y >> 32), (uint32_t)(n2.y >> 32), vhi,
            (uint32_t)(n4.y >> 32), (uint32_t)(n5.y >> 32), (uint32_t)(n6.y >> 32));
        select2_store(P1, op, y0 + 2, x);

        // Tail: ingest rows y0+7..y0+10 (mask past bottom), write batch 1.
        const bool ok8 = (y0 + 8) < IMG_H, ok9 = (y0 + 9) < IMG_H,
                   ok10 = (y0 + 10) < IMG_H;
        roll2(vlo, vhi, quant6(g0), ok8 ? quant6(g1) : 0u);
        sAlo = vlo; sAhi = vhi;                       // V after y0+8
        roll2(vlo, vhi, ok9 ? quant6(g2) : 0u, ok10 ? quant6(g3) : 0u);
        VL[1][3 + x] = make_ulonglong2(((u64)sAhi << 32) | sAlo,
                                       ((u64)vhi  << 32) | vlo);
        __syncthreads();
    }

    // ---- Super-epoch 1: outputs y0+4..y0+7 ----
    {
        const ulonglong2* qp = &VL[1][x];
        ulonglong2 n0 = qp[0], n1 = qp[1], n2 = qp[2];
        ulonglong2 n4 = qp[4], n5 = qp[5], n6 = qp[6];

        // Pair 0 (outputs y0+4, y0+5): V after y0+8 = snapshot.
        Planes6 P0 = transpose6(
            (uint32_t)n0.x, (uint32_t)n1.x, (uint32_t)n2.x, sAlo,
            (uint32_t)n4.x, (uint32_t)n5.x, (uint32_t)n6.x,
            (uint32_t)(n0.x >> 32), (uint32_t)(n1.x >> 32), (uint32_t)(n2.x >> 32), sAhi,
            (uint32_t)(n4.x >> 32), (uint32_t)(n5.x >> 32), (uint32_t)(n6.x >> 32));
        select2_store(P0, op, y0 + 4, x);

        // Pair 1 (outputs y0+6, y0+7): V after y0+10 = current.
        Planes6 P1 = transpose6(
            (uint32_t)n0.y, (uint32_t)n1.y, (uint32_t)n2.y, vlo,
            (uint32_t)n4.y, (uint32_t)n5.y, (uint32_t)n6.y,
            (uint32_t)(n0.y >> 32), (uint32_t)(n1.y >> 32), (uint32_t)(n2.y >> 32), vhi,
            (uint32_t)(n4.y >> 32), (uint32_t)(n5.y >> 32), (uint32_t)(n6.y >> 32));
        select2_store(P1, op, y0 + 6, x);
    }
}

extern "C" void kernel_launch(void* const* d_in, const int* in_sizes, int n_in,
                              void* d_out, int out_size, void* d_ws, size_t ws_size,
                              hipStream_t stream) {
    const float* img = (const float*)d_in[0];   // image; cover_image unused
    float* out = (float*)d_out;
    const int planes = in_sizes[0] / (IMG_H * IMG_W);   // 16*3 = 48
    dim3 grid(planes * RUNS);                   // 1536 blocks
    dim3 block(256);
    median7_kernel<<<grid, block, 0, stream>>>(img, out);
}